// Round 2
// baseline (245.664 us; speedup 1.0000x reference)
//
#include <hip/hip_runtime.h>
#include <math.h>

#define NN 20000
#define EE 320000
#define CIN 16
#define COUT 16
#define R2C 0.25f
#define PROW 1024   // 64 cells * 16 outputs
#define P_OFF 81920 // cnt occupies [0, NN*4) = 80000 B; P starts after, 16B-aligned

// ---------------- zero out + counts ----------------
__global__ __launch_bounds__(256) void k_zero(float* __restrict__ out, int* __restrict__ cnt) {
    int i = blockIdx.x * 256 + threadIdx.x;
    if (i < NN * COUT) out[i] = 0.0f;
    if (i < NN) cnt[i] = 0;
}

// ---------------- P GEMM: P[n][cell][o] = sum_ci feat[n][ci] * filters[cell][ci][o] ----------------
// Block = 256 threads = 4 waves. Each wave: 64 lanes = 64 consecutive nodes, wave id = cell group.
// Filter addresses are wave-uniform (depend only on cell/ci loop counters) -> scalar loads.
__global__ __launch_bounds__(256) void k_pgemm(const float* __restrict__ feat,
                                               const float* __restrict__ filt,
                                               float* __restrict__ P) {
    int lane = threadIdx.x & 63;
    int cg   = threadIdx.x >> 6;          // 0..3 -> cells [cg*16, cg*16+16)
    int n    = blockIdx.x * 64 + lane;
    if (n >= NN) return;

    float f[16];
    const float4* fp = (const float4*)(feat + (size_t)n * 16);
    float4 f0 = fp[0], f1 = fp[1], f2 = fp[2], f3 = fp[3];
    f[0]=f0.x; f[1]=f0.y; f[2]=f0.z; f[3]=f0.w;
    f[4]=f1.x; f[5]=f1.y; f[6]=f1.z; f[7]=f1.w;
    f[8]=f2.x; f[9]=f2.y; f[10]=f2.z; f[11]=f2.w;
    f[12]=f3.x; f[13]=f3.y; f[14]=f3.z; f[15]=f3.w;

    for (int cell = cg * 16; cell < cg * 16 + 16; ++cell) {
        float4 a0 = make_float4(0.f,0.f,0.f,0.f);
        float4 a1 = a0, a2 = a0, a3 = a0;
        const float4* frow = (const float4*)(filt + (size_t)cell * 256);
        #pragma unroll
        for (int ci = 0; ci < 16; ++ci) {
            float fv = f[ci];
            float4 w0 = frow[ci*4+0];
            float4 w1 = frow[ci*4+1];
            float4 w2 = frow[ci*4+2];
            float4 w3 = frow[ci*4+3];
            a0.x = fmaf(fv, w0.x, a0.x); a0.y = fmaf(fv, w0.y, a0.y);
            a0.z = fmaf(fv, w0.z, a0.z); a0.w = fmaf(fv, w0.w, a0.w);
            a1.x = fmaf(fv, w1.x, a1.x); a1.y = fmaf(fv, w1.y, a1.y);
            a1.z = fmaf(fv, w1.z, a1.z); a1.w = fmaf(fv, w1.w, a1.w);
            a2.x = fmaf(fv, w2.x, a2.x); a2.y = fmaf(fv, w2.y, a2.y);
            a2.z = fmaf(fv, w2.z, a2.z); a2.w = fmaf(fv, w2.w, a2.w);
            a3.x = fmaf(fv, w3.x, a3.x); a3.y = fmaf(fv, w3.y, a3.y);
            a3.z = fmaf(fv, w3.z, a3.z); a3.w = fmaf(fv, w3.w, a3.w);
        }
        float4* dst = (float4*)(P + (size_t)n * PROW + cell * 16);
        dst[0] = a0; dst[1] = a1; dst[2] = a2; dst[3] = a3;
    }
}

// ---------------- geometry helper (device inline) ----------------
__device__ __forceinline__ bool edge_geom(const float* __restrict__ pos, int row, int col,
                                          float& win,
                                          int ia[2], int jb[2], int kc[2],
                                          float wa[2], float wb[2], float wc[2]) {
    float rx = pos[col*3+0] - pos[row*3+0];
    float ry = pos[col*3+1] - pos[row*3+1];
    float rz = pos[col*3+2] - pos[row*3+2];
    float d2 = rx*rx + ry*ry + rz*rz;
    if (!(d2 < R2C)) return false;           // window == 0 -> contributes nothing
    float u = 1.0f - d2 / R2C;
    win = u * u * u;
    float nr = sqrtf(d2);
    float s  = tanhf(nr) / (nr + 1e-8f);
    float gx = (rx * s + 1.0f) * 1.5f;       // c-axis (k index)
    float gy = (ry * s + 1.0f) * 1.5f;       // b-axis (j index)
    float gz = (rz * s + 1.0f) * 1.5f;       // a-axis (i index)
    float af = floorf(gz), bf = floorf(gy), cf = floorf(gx);
    int ia0 = min(max((int)af, 0), 3);
    int ib0 = min(max((int)bf, 0), 3);
    int ic0 = min(max((int)cf, 0), 3);
    ia[0] = ia0; ia[1] = min(ia0 + 1, 3);
    jb[0] = ib0; jb[1] = min(ib0 + 1, 3);
    kc[0] = ic0; kc[1] = min(ic0 + 1, 3);
    float ad = gz - af, bd = gy - bf, cd = gx - cf;
    wa[0] = 1.0f - ad; wa[1] = ad;
    wb[0] = 1.0f - bd; wb[1] = bd;
    wc[0] = 1.0f - cd; wc[1] = cd;
    return true;
}

// ---------------- edge pass using precomputed P ----------------
__global__ __launch_bounds__(256) void k_edge(const float* __restrict__ pos,
                                              const int* __restrict__ ei,
                                              const float* __restrict__ P,
                                              float* __restrict__ out,
                                              int* __restrict__ cnt) {
    int e = blockIdx.x * 256 + threadIdx.x;
    if (e >= EE) return;
    int row = ei[e];
    int col = ei[EE + e];
    atomicAdd(&cnt[row], 1);

    float win;
    int ia[2], jb[2], kc[2];
    float wa[2], wb[2], wc[2];
    if (!edge_geom(pos, row, col, win, ia, jb, kc, wa, wb, wc)) return;

    float4 a0 = make_float4(0.f,0.f,0.f,0.f);
    float4 a1 = a0, a2 = a0, a3 = a0;
    const float* Pn = P + (size_t)col * PROW;
    #pragma unroll
    for (int da = 0; da < 2; ++da)
    #pragma unroll
    for (int db = 0; db < 2; ++db)
    #pragma unroll
    for (int dc = 0; dc < 2; ++dc) {
        float w = wa[da] * wb[db] * wc[dc] * win;
        const float4* pp = (const float4*)(Pn + (ia[da]*16 + jb[db]*4 + kc[dc]) * 16);
        float4 p0 = pp[0], p1 = pp[1], p2 = pp[2], p3 = pp[3];
        a0.x = fmaf(w, p0.x, a0.x); a0.y = fmaf(w, p0.y, a0.y);
        a0.z = fmaf(w, p0.z, a0.z); a0.w = fmaf(w, p0.w, a0.w);
        a1.x = fmaf(w, p1.x, a1.x); a1.y = fmaf(w, p1.y, a1.y);
        a1.z = fmaf(w, p1.z, a1.z); a1.w = fmaf(w, p1.w, a1.w);
        a2.x = fmaf(w, p2.x, a2.x); a2.y = fmaf(w, p2.y, a2.y);
        a2.z = fmaf(w, p2.z, a2.z); a2.w = fmaf(w, p2.w, a2.w);
        a3.x = fmaf(w, p3.x, a3.x); a3.y = fmaf(w, p3.y, a3.y);
        a3.z = fmaf(w, p3.z, a3.z); a3.w = fmaf(w, p3.w, a3.w);
    }
    float* op = out + (size_t)row * 16;
    atomicAdd(op+0,  a0.x); atomicAdd(op+1,  a0.y); atomicAdd(op+2,  a0.z); atomicAdd(op+3,  a0.w);
    atomicAdd(op+4,  a1.x); atomicAdd(op+5,  a1.y); atomicAdd(op+6,  a1.z); atomicAdd(op+7,  a1.w);
    atomicAdd(op+8,  a2.x); atomicAdd(op+9,  a2.y); atomicAdd(op+10, a2.z); atomicAdd(op+11, a2.w);
    atomicAdd(op+12, a3.x); atomicAdd(op+13, a3.y); atomicAdd(op+14, a3.z); atomicAdd(op+15, a3.w);
}

// ---------------- fallback: direct edge kernel, filters from global (slow but correct) ----------------
__global__ __launch_bounds__(256) void k_edge_direct(const float* __restrict__ pos,
                                                     const float* __restrict__ feat,
                                                     const float* __restrict__ filt,
                                                     const int* __restrict__ ei,
                                                     float* __restrict__ out,
                                                     int* __restrict__ cnt) {
    int e = blockIdx.x * 256 + threadIdx.x;
    if (e >= EE) return;
    int row = ei[e];
    int col = ei[EE + e];
    atomicAdd(&cnt[row], 1);

    float win;
    int ia[2], jb[2], kc[2];
    float wa[2], wb[2], wc[2];
    if (!edge_geom(pos, row, col, win, ia, jb, kc, wa, wb, wc)) return;

    float fv[16];
    const float4* fp = (const float4*)(feat + (size_t)col * 16);
    float4 f0 = fp[0], f1 = fp[1], f2 = fp[2], f3 = fp[3];
    fv[0]=f0.x; fv[1]=f0.y; fv[2]=f0.z; fv[3]=f0.w;
    fv[4]=f1.x; fv[5]=f1.y; fv[6]=f1.z; fv[7]=f1.w;
    fv[8]=f2.x; fv[9]=f2.y; fv[10]=f2.z; fv[11]=f2.w;
    fv[12]=f3.x; fv[13]=f3.y; fv[14]=f3.z; fv[15]=f3.w;

    float4 a0 = make_float4(0.f,0.f,0.f,0.f);
    float4 a1 = a0, a2 = a0, a3 = a0;
    for (int da = 0; da < 2; ++da)
    for (int db = 0; db < 2; ++db)
    for (int dc = 0; dc < 2; ++dc) {
        float w = wa[da] * wb[db] * wc[dc] * win;
        const float* fb = filt + (size_t)(ia[da]*16 + jb[db]*4 + kc[dc]) * 256;
        #pragma unroll
        for (int ci = 0; ci < 16; ++ci) {
            float c = w * fv[ci];
            const float4* r4 = (const float4*)(fb + ci * 16);
            float4 w0 = r4[0], w1 = r4[1], w2 = r4[2], w3 = r4[3];
            a0.x = fmaf(c, w0.x, a0.x); a0.y = fmaf(c, w0.y, a0.y);
            a0.z = fmaf(c, w0.z, a0.z); a0.w = fmaf(c, w0.w, a0.w);
            a1.x = fmaf(c, w1.x, a1.x); a1.y = fmaf(c, w1.y, a1.y);
            a1.z = fmaf(c, w1.z, a1.z); a1.w = fmaf(c, w1.w, a1.w);
            a2.x = fmaf(c, w2.x, a2.x); a2.y = fmaf(c, w2.y, a2.y);
            a2.z = fmaf(c, w2.z, a2.z); a2.w = fmaf(c, w2.w, a2.w);
            a3.x = fmaf(c, w3.x, a3.x); a3.y = fmaf(c, w3.y, a3.y);
            a3.w = fmaf(c, w3.w, a3.w); a3.z = fmaf(c, w3.z, a3.z);
        }
    }
    float* op = out + (size_t)row * 16;
    atomicAdd(op+0,  a0.x); atomicAdd(op+1,  a0.y); atomicAdd(op+2,  a0.z); atomicAdd(op+3,  a0.w);
    atomicAdd(op+4,  a1.x); atomicAdd(op+5,  a1.y); atomicAdd(op+6,  a1.z); atomicAdd(op+7,  a1.w);
    atomicAdd(op+8,  a2.x); atomicAdd(op+9,  a2.y); atomicAdd(op+10, a2.z); atomicAdd(op+11, a2.w);
    atomicAdd(op+12, a3.x); atomicAdd(op+13, a3.y); atomicAdd(op+14, a3.z); atomicAdd(op+15, a3.w);
}

// ---------------- divide by max(cnt,1) ----------------
__global__ __launch_bounds__(256) void k_div(float* __restrict__ out, const int* __restrict__ cnt) {
    int i = blockIdx.x * 256 + threadIdx.x;
    if (i >= NN * COUT) return;
    int c = cnt[i >> 4];
    float denom = (c > 1) ? (float)c : 1.0f;
    out[i] = out[i] / denom;
}

extern "C" void kernel_launch(void* const* d_in, const int* in_sizes, int n_in,
                              void* d_out, int out_size, void* d_ws, size_t ws_size,
                              hipStream_t stream) {
    const float* pos  = (const float*)d_in[0];
    const float* feat = (const float*)d_in[1];
    const float* filt = (const float*)d_in[2];
    const int*   ei   = (const int*)d_in[3];
    float* out = (float*)d_out;

    int* cnt = (int*)d_ws;
    size_t need = (size_t)P_OFF + (size_t)NN * PROW * sizeof(float);

    k_zero<<<(NN * COUT + 255) / 256, 256, 0, stream>>>(out, cnt);

    if (ws_size >= need) {
        float* P = (float*)((char*)d_ws + P_OFF);
        k_pgemm<<<(NN + 63) / 64, 256, 0, stream>>>(feat, filt, P);
        k_edge<<<(EE + 255) / 256, 256, 0, stream>>>(pos, ei, P, out, cnt);
    } else {
        k_edge_direct<<<(EE + 255) / 256, 256, 0, stream>>>(pos, feat, filt, ei, out, cnt);
    }

    k_div<<<(NN * COUT + 255) / 256, 256, 0, stream>>>(out, cnt);
}

// Round 3
// 159.983 us; speedup vs baseline: 1.5356x; 1.5356x over previous
//
#include <hip/hip_runtime.h>
#include <math.h>

#define NN 20000
#define EE 320000
#define CIN 16
#define COUT 16
#define R2C 0.25f
#define PROW 1024   // 64 cells * 16 outputs
#define P_OFF 81920 // cnt occupies [0, NN*4) = 80000 B; P starts after, 16B-aligned

// ---------------- zero out + counts ----------------
__global__ __launch_bounds__(256) void k_zero(float* __restrict__ out, int* __restrict__ cnt) {
    int i = blockIdx.x * 256 + threadIdx.x;
    if (i < NN * COUT) out[i] = 0.0f;
    if (i < NN) cnt[i] = 0;
}

// ---------------- P GEMM: P[n][cell][o] = sum_ci feat[n][ci] * filters[cell][ci][o] ----------------
// Block = 256 threads = 4 waves; wave = 64 consecutive nodes. Cell range split over
// (blockIdx.y, wave) -> 4 cells each => grid (313,4) = 1252 blocks (vs 313 before).
// Filter addresses stay wave-uniform -> broadcast loads, filt traffic ~free.
__global__ __launch_bounds__(256) void k_pgemm(const float* __restrict__ feat,
                                               const float* __restrict__ filt,
                                               float* __restrict__ P) {
    int lane = threadIdx.x & 63;
    int w    = threadIdx.x >> 6;                 // 0..3
    int cg   = blockIdx.y * 4 + w;               // 0..15 -> cells [cg*4, cg*4+4)
    int n    = blockIdx.x * 64 + lane;
    if (n >= NN) return;

    float f[16];
    const float4* fp = (const float4*)(feat + (size_t)n * 16);
    float4 f0 = fp[0], f1 = fp[1], f2 = fp[2], f3 = fp[3];
    f[0]=f0.x; f[1]=f0.y; f[2]=f0.z; f[3]=f0.w;
    f[4]=f1.x; f[5]=f1.y; f[6]=f1.z; f[7]=f1.w;
    f[8]=f2.x; f[9]=f2.y; f[10]=f2.z; f[11]=f2.w;
    f[12]=f3.x; f[13]=f3.y; f[14]=f3.z; f[15]=f3.w;

    for (int cell = cg * 4; cell < cg * 4 + 4; ++cell) {
        float4 a0 = make_float4(0.f,0.f,0.f,0.f);
        float4 a1 = a0, a2 = a0, a3 = a0;
        const float4* frow = (const float4*)(filt + (size_t)cell * 256);
        #pragma unroll
        for (int ci = 0; ci < 16; ++ci) {
            float fv = f[ci];
            float4 w0 = frow[ci*4+0];
            float4 w1 = frow[ci*4+1];
            float4 w2 = frow[ci*4+2];
            float4 w3 = frow[ci*4+3];
            a0.x = fmaf(fv, w0.x, a0.x); a0.y = fmaf(fv, w0.y, a0.y);
            a0.z = fmaf(fv, w0.z, a0.z); a0.w = fmaf(fv, w0.w, a0.w);
            a1.x = fmaf(fv, w1.x, a1.x); a1.y = fmaf(fv, w1.y, a1.y);
            a1.z = fmaf(fv, w1.z, a1.z); a1.w = fmaf(fv, w1.w, a1.w);
            a2.x = fmaf(fv, w2.x, a2.x); a2.y = fmaf(fv, w2.y, a2.y);
            a2.z = fmaf(fv, w2.z, a2.z); a2.w = fmaf(fv, w2.w, a2.w);
            a3.x = fmaf(fv, w3.x, a3.x); a3.y = fmaf(fv, w3.y, a3.y);
            a3.z = fmaf(fv, w3.z, a3.z); a3.w = fmaf(fv, w3.w, a3.w);
        }
        float4* dst = (float4*)(P + (size_t)n * PROW + cell * 16);
        dst[0] = a0; dst[1] = a1; dst[2] = a2; dst[3] = a3;
    }
}

// ---------------- geometry helper (device inline) ----------------
__device__ __forceinline__ bool edge_geom(const float* __restrict__ pos, int row, int col,
                                          float& win,
                                          int ia[2], int jb[2], int kc[2],
                                          float wa[2], float wb[2], float wc[2]) {
    float rx = pos[col*3+0] - pos[row*3+0];
    float ry = pos[col*3+1] - pos[row*3+1];
    float rz = pos[col*3+2] - pos[row*3+2];
    float d2 = rx*rx + ry*ry + rz*rz;
    if (!(d2 < R2C)) return false;           // window == 0 -> contributes nothing
    float u = 1.0f - d2 / R2C;
    win = u * u * u;
    float nr = sqrtf(d2);
    float s  = tanhf(nr) / (nr + 1e-8f);
    float gx = (rx * s + 1.0f) * 1.5f;       // c-axis (k index)
    float gy = (ry * s + 1.0f) * 1.5f;       // b-axis (j index)
    float gz = (rz * s + 1.0f) * 1.5f;       // a-axis (i index)
    float af = floorf(gz), bf = floorf(gy), cf = floorf(gx);
    int ia0 = min(max((int)af, 0), 3);
    int ib0 = min(max((int)bf, 0), 3);
    int ic0 = min(max((int)cf, 0), 3);
    ia[0] = ia0; ia[1] = min(ia0 + 1, 3);
    jb[0] = ib0; jb[1] = min(ib0 + 1, 3);
    kc[0] = ic0; kc[1] = min(ic0 + 1, 3);
    float ad = gz - af, bd = gy - bf, cd = gx - cf;
    wa[0] = 1.0f - ad; wa[1] = ad;
    wb[0] = 1.0f - bd; wb[1] = bd;
    wc[0] = 1.0f - cd; wc[1] = cd;
    return true;
}

// ---------------- edge pass: 4 threads per edge, each owns a channel quad ----------------
// lanes 4k..4k+3 share edge e; their 4 float4 gathers per corner form one 64B segment.
__global__ __launch_bounds__(256) void k_edge(const float* __restrict__ pos,
                                              const int* __restrict__ ei,
                                              const float* __restrict__ P,
                                              float* __restrict__ out,
                                              int* __restrict__ cnt) {
    int t = blockIdx.x * 256 + threadIdx.x;
    int e = t >> 2;
    int q = t & 3;                   // channel quad: outputs [q*4, q*4+4)
    if (e >= EE) return;
    int row = ei[e];
    int col = ei[EE + e];
    if (q == 0) atomicAdd(&cnt[row], 1);

    float win;
    int ia[2], jb[2], kc[2];
    float wa[2], wb[2], wc[2];
    if (!edge_geom(pos, row, col, win, ia, jb, kc, wa, wb, wc)) return;

    float4 acc = make_float4(0.f,0.f,0.f,0.f);
    const float* Pn = P + (size_t)col * PROW + q * 4;
    #pragma unroll
    for (int da = 0; da < 2; ++da)
    #pragma unroll
    for (int db = 0; db < 2; ++db)
    #pragma unroll
    for (int dc = 0; dc < 2; ++dc) {
        float w = wa[da] * wb[db] * wc[dc] * win;
        float4 p = *(const float4*)(Pn + (ia[da]*16 + jb[db]*4 + kc[dc]) * 16);
        acc.x = fmaf(w, p.x, acc.x);
        acc.y = fmaf(w, p.y, acc.y);
        acc.z = fmaf(w, p.z, acc.z);
        acc.w = fmaf(w, p.w, acc.w);
    }
    float* op = out + (size_t)row * 16 + q * 4;
    atomicAdd(op+0, acc.x);
    atomicAdd(op+1, acc.y);
    atomicAdd(op+2, acc.z);
    atomicAdd(op+3, acc.w);
}

// ---------------- fallback: direct edge kernel, filters from global (slow but correct) ----------------
__global__ __launch_bounds__(256) void k_edge_direct(const float* __restrict__ pos,
                                                     const float* __restrict__ feat,
                                                     const float* __restrict__ filt,
                                                     const int* __restrict__ ei,
                                                     float* __restrict__ out,
                                                     int* __restrict__ cnt) {
    int e = blockIdx.x * 256 + threadIdx.x;
    if (e >= EE) return;
    int row = ei[e];
    int col = ei[EE + e];
    atomicAdd(&cnt[row], 1);

    float win;
    int ia[2], jb[2], kc[2];
    float wa[2], wb[2], wc[2];
    if (!edge_geom(pos, row, col, win, ia, jb, kc, wa, wb, wc)) return;

    float fv[16];
    const float4* fp = (const float4*)(feat + (size_t)col * 16);
    float4 f0 = fp[0], f1 = fp[1], f2 = fp[2], f3 = fp[3];
    fv[0]=f0.x; fv[1]=f0.y; fv[2]=f0.z; fv[3]=f0.w;
    fv[4]=f1.x; fv[5]=f1.y; fv[6]=f1.z; fv[7]=f1.w;
    fv[8]=f2.x; fv[9]=f2.y; fv[10]=f2.z; fv[11]=f2.w;
    fv[12]=f3.x; fv[13]=f3.y; fv[14]=f3.z; fv[15]=f3.w;

    float4 a0 = make_float4(0.f,0.f,0.f,0.f);
    float4 a1 = a0, a2 = a0, a3 = a0;
    for (int da = 0; da < 2; ++da)
    for (int db = 0; db < 2; ++db)
    for (int dc = 0; dc < 2; ++dc) {
        float w = wa[da] * wb[db] * wc[dc] * win;
        const float* fb = filt + (size_t)(ia[da]*16 + jb[db]*4 + kc[dc]) * 256;
        #pragma unroll
        for (int ci = 0; ci < 16; ++ci) {
            float c = w * fv[ci];
            const float4* r4 = (const float4*)(fb + ci * 16);
            float4 w0 = r4[0], w1 = r4[1], w2 = r4[2], w3 = r4[3];
            a0.x = fmaf(c, w0.x, a0.x); a0.y = fmaf(c, w0.y, a0.y);
            a0.z = fmaf(c, w0.z, a0.z); a0.w = fmaf(c, w0.w, a0.w);
            a1.x = fmaf(c, w1.x, a1.x); a1.y = fmaf(c, w1.y, a1.y);
            a1.z = fmaf(c, w1.z, a1.z); a1.w = fmaf(c, w1.w, a1.w);
            a2.x = fmaf(c, w2.x, a2.x); a2.y = fmaf(c, w2.y, a2.y);
            a2.z = fmaf(c, w2.z, a2.z); a2.w = fmaf(c, w2.w, a2.w);
            a3.x = fmaf(c, w3.x, a3.x); a3.y = fmaf(c, w3.y, a3.y);
            a3.z = fmaf(c, w3.z, a3.z); a3.w = fmaf(c, w3.w, a3.w);
        }
    }
    float* op = out + (size_t)row * 16;
    atomicAdd(op+0,  a0.x); atomicAdd(op+1,  a0.y); atomicAdd(op+2,  a0.z); atomicAdd(op+3,  a0.w);
    atomicAdd(op+4,  a1.x); atomicAdd(op+5,  a1.y); atomicAdd(op+6,  a1.z); atomicAdd(op+7,  a1.w);
    atomicAdd(op+8,  a2.x); atomicAdd(op+9,  a2.y); atomicAdd(op+10, a2.z); atomicAdd(op+11, a2.w);
    atomicAdd(op+12, a3.x); atomicAdd(op+13, a3.y); atomicAdd(op+14, a3.z); atomicAdd(op+15, a3.w);
}

// ---------------- divide by max(cnt,1) ----------------
__global__ __launch_bounds__(256) void k_div(float* __restrict__ out, const int* __restrict__ cnt) {
    int i = blockIdx.x * 256 + threadIdx.x;
    if (i >= NN * COUT) return;
    int c = cnt[i >> 4];
    float denom = (c > 1) ? (float)c : 1.0f;
    out[i] = out[i] / denom;
}

extern "C" void kernel_launch(void* const* d_in, const int* in_sizes, int n_in,
                              void* d_out, int out_size, void* d_ws, size_t ws_size,
                              hipStream_t stream) {
    const float* pos  = (const float*)d_in[0];
    const float* feat = (const float*)d_in[1];
    const float* filt = (const float*)d_in[2];
    const int*   ei   = (const int*)d_in[3];
    float* out = (float*)d_out;

    int* cnt = (int*)d_ws;
    size_t need = (size_t)P_OFF + (size_t)NN * PROW * sizeof(float);

    k_zero<<<(NN * COUT + 255) / 256, 256, 0, stream>>>(out, cnt);

    if (ws_size >= need) {
        float* P = (float*)((char*)d_ws + P_OFF);
        dim3 pg((NN + 63) / 64, 4);
        k_pgemm<<<pg, 256, 0, stream>>>(feat, filt, P);
        k_edge<<<(EE * 4 + 255) / 256, 256, 0, stream>>>(pos, ei, P, out, cnt);
    } else {
        k_edge_direct<<<(EE + 255) / 256, 256, 0, stream>>>(pos, feat, filt, ei, out, cnt);
    }

    k_div<<<(NN * COUT + 255) / 256, 256, 0, stream>>>(out, cnt);
}

// Round 4
// 135.340 us; speedup vs baseline: 1.8152x; 1.1821x over previous
//
#include <hip/hip_runtime.h>
#include <math.h>

#define NN 20000
#define EE 320000
#define CIN 16
#define COUT 16
#define R2C 0.25f
#define P_OFF 81920 // cnt occupies [0, NN*4) = 80000 B; P starts after, 16B-aligned
// P layout: P[cell][node][out] -> P[((size_t)cell*NN + n)*16 + o], 64 cells -> 82 MB

// ---------------- zero out + counts ----------------
__global__ __launch_bounds__(256) void k_zero(float* __restrict__ out, int* __restrict__ cnt) {
    int i = blockIdx.x * 256 + threadIdx.x;
    if (i < NN * COUT) out[i] = 0.0f;
    if (i < NN) cnt[i] = 0;
}

// ---------------- P GEMM: P[cell][n][o] = sum_ci feat[n][ci] * filters[cell][ci][o] ----------------
// Grid (ceil(NN/64), 4): blockIdx.y picks 16 cells, staged into 16 KB LDS.
// Block 256 = 4 waves; wave = 16 nodes; lane = node_sub*4 + q (q = output quad).
// Stores: lane i writes 16 B at base + i*16 -> one contiguous 1 KB segment per wave store.
__global__ __launch_bounds__(256) void k_pgemm(const float* __restrict__ feat,
                                               const float* __restrict__ filt,
                                               float* __restrict__ P) {
    __shared__ float fl[16 * 256]; // 16 cells * 16ci * 16co

    // stage this block's 16 cells of filters: 16 KB, coalesced float4
    {
        const float4* src = (const float4*)(filt + (size_t)blockIdx.y * 16 * 256);
        float4* dst = (float4*)fl;
        #pragma unroll
        for (int r = 0; r < 4; ++r)
            dst[r * 256 + threadIdx.x] = src[r * 256 + threadIdx.x];
    }
    __syncthreads();

    int lane = threadIdx.x & 63;
    int w    = threadIdx.x >> 6;
    int q    = lane & 3;            // output quad
    int ns   = lane >> 2;           // node sub 0..15
    int n    = blockIdx.x * 64 + w * 16 + ns;
    if (n >= NN) return;

    float f[16];
    {
        const float4* fp = (const float4*)(feat + (size_t)n * 16);
        float4 f0 = fp[0], f1 = fp[1], f2 = fp[2], f3 = fp[3];
        f[0]=f0.x; f[1]=f0.y; f[2]=f0.z; f[3]=f0.w;
        f[4]=f1.x; f[5]=f1.y; f[6]=f1.z; f[7]=f1.w;
        f[8]=f2.x; f[9]=f2.y; f[10]=f2.z; f[11]=f2.w;
        f[12]=f3.x; f[13]=f3.y; f[14]=f3.z; f[15]=f3.w;
    }

    for (int cell = 0; cell < 16; ++cell) {
        float4 acc = make_float4(0.f,0.f,0.f,0.f);
        const float4* row = (const float4*)(fl + cell * 256) + q;
        #pragma unroll
        for (int ci = 0; ci < 16; ++ci) {
            float4 wv = row[ci * 4];
            float fv = f[ci];
            acc.x = fmaf(fv, wv.x, acc.x);
            acc.y = fmaf(fv, wv.y, acc.y);
            acc.z = fmaf(fv, wv.z, acc.z);
            acc.w = fmaf(fv, wv.w, acc.w);
        }
        size_t cell_g = (size_t)(blockIdx.y * 16 + cell);
        *(float4*)(P + (cell_g * NN + n) * 16 + q * 4) = acc;
    }
}

// ---------------- geometry helper (device inline) ----------------
__device__ __forceinline__ bool edge_geom(const float* __restrict__ pos, int row, int col,
                                          float& win,
                                          int ia[2], int jb[2], int kc[2],
                                          float wa[2], float wb[2], float wc[2]) {
    float rx = pos[col*3+0] - pos[row*3+0];
    float ry = pos[col*3+1] - pos[row*3+1];
    float rz = pos[col*3+2] - pos[row*3+2];
    float d2 = rx*rx + ry*ry + rz*rz;
    if (!(d2 < R2C)) return false;           // window == 0 -> contributes nothing
    float u = 1.0f - d2 / R2C;
    win = u * u * u;
    float nr = sqrtf(d2);
    float s  = tanhf(nr) / (nr + 1e-8f);
    float gx = (rx * s + 1.0f) * 1.5f;       // c-axis (k index)
    float gy = (ry * s + 1.0f) * 1.5f;       // b-axis (j index)
    float gz = (rz * s + 1.0f) * 1.5f;       // a-axis (i index)
    float af = floorf(gz), bf = floorf(gy), cf = floorf(gx);
    int ia0 = min(max((int)af, 0), 3);
    int ib0 = min(max((int)bf, 0), 3);
    int ic0 = min(max((int)cf, 0), 3);
    ia[0] = ia0; ia[1] = min(ia0 + 1, 3);
    jb[0] = ib0; jb[1] = min(ib0 + 1, 3);
    kc[0] = ic0; kc[1] = min(ic0 + 1, 3);
    float ad = gz - af, bd = gy - bf, cd = gx - cf;
    wa[0] = 1.0f - ad; wa[1] = ad;
    wb[0] = 1.0f - bd; wb[1] = bd;
    wc[0] = 1.0f - cd; wc[1] = cd;
    return true;
}

// ---------------- edge pass: 4 threads per edge, each owns a channel quad ----------------
// lanes 4k..4k+3 share edge e; their 4 float4 gathers per corner form one 64B segment.
__global__ __launch_bounds__(256) void k_edge(const float* __restrict__ pos,
                                              const int* __restrict__ ei,
                                              const float* __restrict__ P,
                                              float* __restrict__ out,
                                              int* __restrict__ cnt) {
    int t = blockIdx.x * 256 + threadIdx.x;
    int e = t >> 2;
    int q = t & 3;                   // channel quad: outputs [q*4, q*4+4)
    if (e >= EE) return;
    int row = ei[e];
    int col = ei[EE + e];
    if (q == 0) atomicAdd(&cnt[row], 1);

    float win;
    int ia[2], jb[2], kc[2];
    float wa[2], wb[2], wc[2];
    if (!edge_geom(pos, row, col, win, ia, jb, kc, wa, wb, wc)) return;

    float4 acc = make_float4(0.f,0.f,0.f,0.f);
    const float* Pq = P + (size_t)col * 16 + q * 4;
    #pragma unroll
    for (int da = 0; da < 2; ++da)
    #pragma unroll
    for (int db = 0; db < 2; ++db)
    #pragma unroll
    for (int dc = 0; dc < 2; ++dc) {
        float w = wa[da] * wb[db] * wc[dc] * win;
        int cell = ia[da]*16 + jb[db]*4 + kc[dc];
        float4 p = *(const float4*)(Pq + (size_t)cell * NN * 16);
        acc.x = fmaf(w, p.x, acc.x);
        acc.y = fmaf(w, p.y, acc.y);
        acc.z = fmaf(w, p.z, acc.z);
        acc.w = fmaf(w, p.w, acc.w);
    }
    float* op = out + (size_t)row * 16 + q * 4;
    atomicAdd(op+0, acc.x);
    atomicAdd(op+1, acc.y);
    atomicAdd(op+2, acc.z);
    atomicAdd(op+3, acc.w);
}

// ---------------- fallback: direct edge kernel, filters from global (slow but correct) ----------------
__global__ __launch_bounds__(256) void k_edge_direct(const float* __restrict__ pos,
                                                     const float* __restrict__ feat,
                                                     const float* __restrict__ filt,
                                                     const int* __restrict__ ei,
                                                     float* __restrict__ out,
                                                     int* __restrict__ cnt) {
    int e = blockIdx.x * 256 + threadIdx.x;
    if (e >= EE) return;
    int row = ei[e];
    int col = ei[EE + e];
    atomicAdd(&cnt[row], 1);

    float win;
    int ia[2], jb[2], kc[2];
    float wa[2], wb[2], wc[2];
    if (!edge_geom(pos, row, col, win, ia, jb, kc, wa, wb, wc)) return;

    float fv[16];
    const float4* fp = (const float4*)(feat + (size_t)col * 16);
    float4 f0 = fp[0], f1 = fp[1], f2 = fp[2], f3 = fp[3];
    fv[0]=f0.x; fv[1]=f0.y; fv[2]=f0.z; fv[3]=f0.w;
    fv[4]=f1.x; fv[5]=f1.y; fv[6]=f1.z; fv[7]=f1.w;
    fv[8]=f2.x; fv[9]=f2.y; fv[10]=f2.z; fv[11]=f2.w;
    fv[12]=f3.x; fv[13]=f3.y; fv[14]=f3.z; fv[15]=f3.w;

    float4 a0 = make_float4(0.f,0.f,0.f,0.f);
    float4 a1 = a0, a2 = a0, a3 = a0;
    for (int da = 0; da < 2; ++da)
    for (int db = 0; db < 2; ++db)
    for (int dc = 0; dc < 2; ++dc) {
        float w = wa[da] * wb[db] * wc[dc] * win;
        const float* fb = filt + (size_t)(ia[da]*16 + jb[db]*4 + kc[dc]) * 256;
        #pragma unroll
        for (int ci = 0; ci < 16; ++ci) {
            float c = w * fv[ci];
            const float4* r4 = (const float4*)(fb + ci * 16);
            float4 w0 = r4[0], w1 = r4[1], w2 = r4[2], w3 = r4[3];
            a0.x = fmaf(c, w0.x, a0.x); a0.y = fmaf(c, w0.y, a0.y);
            a0.z = fmaf(c, w0.z, a0.z); a0.w = fmaf(c, w0.w, a0.w);
            a1.x = fmaf(c, w1.x, a1.x); a1.y = fmaf(c, w1.y, a1.y);
            a1.z = fmaf(c, w1.z, a1.z); a1.w = fmaf(c, w1.w, a1.w);
            a2.x = fmaf(c, w2.x, a2.x); a2.y = fmaf(c, w2.y, a2.y);
            a2.z = fmaf(c, w2.z, a2.z); a2.w = fmaf(c, w2.w, a2.w);
            a3.x = fmaf(c, w3.x, a3.x); a3.y = fmaf(c, w3.y, a3.y);
            a3.z = fmaf(c, w3.z, a3.z); a3.w = fmaf(c, w3.w, a3.w);
        }
    }
    float* op = out + (size_t)row * 16;
    atomicAdd(op+0,  a0.x); atomicAdd(op+1,  a0.y); atomicAdd(op+2,  a0.z); atomicAdd(op+3,  a0.w);
    atomicAdd(op+4,  a1.x); atomicAdd(op+5,  a1.y); atomicAdd(op+6,  a1.z); atomicAdd(op+7,  a1.w);
    atomicAdd(op+8,  a2.x); atomicAdd(op+9,  a2.y); atomicAdd(op+10, a2.z); atomicAdd(op+11, a2.w);
    atomicAdd(op+12, a3.x); atomicAdd(op+13, a3.y); atomicAdd(op+14, a3.z); atomicAdd(op+15, a3.w);
}

// ---------------- divide by max(cnt,1) ----------------
__global__ __launch_bounds__(256) void k_div(float* __restrict__ out, const int* __restrict__ cnt) {
    int i = blockIdx.x * 256 + threadIdx.x;
    if (i >= NN * COUT) return;
    int c = cnt[i >> 4];
    float denom = (c > 1) ? (float)c : 1.0f;
    out[i] = out[i] / denom;
}

extern "C" void kernel_launch(void* const* d_in, const int* in_sizes, int n_in,
                              void* d_out, int out_size, void* d_ws, size_t ws_size,
                              hipStream_t stream) {
    const float* pos  = (const float*)d_in[0];
    const float* feat = (const float*)d_in[1];
    const float* filt = (const float*)d_in[2];
    const int*   ei   = (const int*)d_in[3];
    float* out = (float*)d_out;

    int* cnt = (int*)d_ws;
    size_t need = (size_t)P_OFF + (size_t)64 * NN * 16 * sizeof(float);

    k_zero<<<(NN * COUT + 255) / 256, 256, 0, stream>>>(out, cnt);

    if (ws_size >= need) {
        float* P = (float*)((char*)d_ws + P_OFF);
        dim3 pg((NN + 63) / 64, 4);
        k_pgemm<<<pg, 256, 0, stream>>>(feat, filt, P);
        k_edge<<<(EE * 4 + 255) / 256, 256, 0, stream>>>(pos, ei, P, out, cnt);
    } else {
        k_edge_direct<<<(EE + 255) / 256, 256, 0, stream>>>(pos, feat, filt, ei, out, cnt);
    }

    k_div<<<(NN * COUT + 255) / 256, 256, 0, stream>>>(out, cnt);
}

// Round 5
// 119.647 us; speedup vs baseline: 2.0532x; 1.1312x over previous
//
#include <hip/hip_runtime.h>
#include <math.h>

#define NN 20000
#define EE 320000
#define CIN 16
#define COUT 16
#define R2C 0.25f
#define P_OFF 81920 // cnt occupies [0, NN*4) = 80000 B; P starts after, 16B-aligned
// P layout: P[cell][node][out] -> P[((size_t)cell*NN + n)*16 + o], 64 cells -> 82 MB

// ---------------- zero out + counts ----------------
__global__ __launch_bounds__(256) void k_zero(float* __restrict__ out, int* __restrict__ cnt) {
    int i = blockIdx.x * 256 + threadIdx.x;
    if (i < NN * COUT) out[i] = 0.0f;
    if (i < NN) cnt[i] = 0;
}

// ---------------- P GEMM: P[cell][n][o] = sum_ci feat[n][ci] * filters[cell][ci][o] ----------------
// Grid (ceil(NN/64), 4): blockIdx.y picks 16 cells -> 16 KB LDS stage.
// Block 256 = 4 waves; wave w owns cells [w*4, w*4+4). Lane = (ns, q); each lane
// processes 4 nodes {base+ns+16r} -> 16 FLOP per LDS b128 load (was 4).
// Stores: lane (ns,q) writes 16 B contiguous -> 1 KB per wave-store, full lines.
__global__ __launch_bounds__(256) void k_pgemm(const float* __restrict__ feat,
                                               const float* __restrict__ filt,
                                               float* __restrict__ P) {
    __shared__ float fl[16 * 256]; // 16 cells * 16ci * 16co

    {
        const float4* src = (const float4*)(filt + (size_t)blockIdx.y * 16 * 256);
        float4* dst = (float4*)fl;
        #pragma unroll
        for (int r = 0; r < 4; ++r)
            dst[r * 256 + threadIdx.x] = src[r * 256 + threadIdx.x];
    }
    __syncthreads();

    int lane  = threadIdx.x & 63;
    int w     = threadIdx.x >> 6;   // wave -> cell sub-group
    int q     = lane & 3;           // output quad
    int ns    = lane >> 2;          // node sub 0..15
    int nbase = blockIdx.x * 64;

    float f[4][16];
    #pragma unroll
    for (int r = 0; r < 4; ++r) {
        int n = nbase + ns + 16 * r;
        if (n < NN) {
            const float4* fp = (const float4*)(feat + (size_t)n * 16);
            float4 f0 = fp[0], f1 = fp[1], f2 = fp[2], f3 = fp[3];
            f[r][0]=f0.x; f[r][1]=f0.y; f[r][2]=f0.z; f[r][3]=f0.w;
            f[r][4]=f1.x; f[r][5]=f1.y; f[r][6]=f1.z; f[r][7]=f1.w;
            f[r][8]=f2.x; f[r][9]=f2.y; f[r][10]=f2.z; f[r][11]=f2.w;
            f[r][12]=f3.x; f[r][13]=f3.y; f[r][14]=f3.z; f[r][15]=f3.w;
        } else {
            #pragma unroll
            for (int ci = 0; ci < 16; ++ci) f[r][ci] = 0.0f;
        }
    }

    #pragma unroll
    for (int c = 0; c < 4; ++c) {
        int cell = w * 4 + c;
        float4 acc0 = make_float4(0.f,0.f,0.f,0.f);
        float4 acc1 = acc0, acc2 = acc0, acc3 = acc0;
        const float4* row = (const float4*)(fl + cell * 256) + q;
        #pragma unroll
        for (int ci = 0; ci < 16; ++ci) {
            float4 wv = row[ci * 4];
            float v0 = f[0][ci], v1 = f[1][ci], v2 = f[2][ci], v3 = f[3][ci];
            acc0.x = fmaf(v0, wv.x, acc0.x); acc0.y = fmaf(v0, wv.y, acc0.y);
            acc0.z = fmaf(v0, wv.z, acc0.z); acc0.w = fmaf(v0, wv.w, acc0.w);
            acc1.x = fmaf(v1, wv.x, acc1.x); acc1.y = fmaf(v1, wv.y, acc1.y);
            acc1.z = fmaf(v1, wv.z, acc1.z); acc1.w = fmaf(v1, wv.w, acc1.w);
            acc2.x = fmaf(v2, wv.x, acc2.x); acc2.y = fmaf(v2, wv.y, acc2.y);
            acc2.z = fmaf(v2, wv.z, acc2.z); acc2.w = fmaf(v2, wv.w, acc2.w);
            acc3.x = fmaf(v3, wv.x, acc3.x); acc3.y = fmaf(v3, wv.y, acc3.y);
            acc3.z = fmaf(v3, wv.z, acc3.z); acc3.w = fmaf(v3, wv.w, acc3.w);
        }
        size_t cell_g = (size_t)(blockIdx.y * 16 + cell);
        float4 accs[4] = {acc0, acc1, acc2, acc3};
        #pragma unroll
        for (int r = 0; r < 4; ++r) {
            int n = nbase + ns + 16 * r;
            if (n < NN)
                *(float4*)(P + (cell_g * NN + n) * 16 + q * 4) = accs[r];
        }
    }
}

// ---------------- geometry helper (device inline) ----------------
__device__ __forceinline__ bool edge_geom(const float* __restrict__ pos, int row, int col,
                                          float& win,
                                          int ia[2], int jb[2], int kc[2],
                                          float wa[2], float wb[2], float wc[2]) {
    float rx = pos[col*3+0] - pos[row*3+0];
    float ry = pos[col*3+1] - pos[row*3+1];
    float rz = pos[col*3+2] - pos[row*3+2];
    float d2 = rx*rx + ry*ry + rz*rz;
    if (!(d2 < R2C)) return false;           // window == 0 -> contributes nothing
    float u = 1.0f - d2 / R2C;
    win = u * u * u;
    float nr = sqrtf(d2);
    float s  = tanhf(nr) / (nr + 1e-8f);
    float gx = (rx * s + 1.0f) * 1.5f;       // c-axis (k index)
    float gy = (ry * s + 1.0f) * 1.5f;       // b-axis (j index)
    float gz = (rz * s + 1.0f) * 1.5f;       // a-axis (i index)
    float af = floorf(gz), bf = floorf(gy), cf = floorf(gx);
    int ia0 = min(max((int)af, 0), 3);
    int ib0 = min(max((int)bf, 0), 3);
    int ic0 = min(max((int)cf, 0), 3);
    ia[0] = ia0; ia[1] = min(ia0 + 1, 3);
    jb[0] = ib0; jb[1] = min(ib0 + 1, 3);
    kc[0] = ic0; kc[1] = min(ic0 + 1, 3);
    float ad = gz - af, bd = gy - bf, cd = gx - cf;
    wa[0] = 1.0f - ad; wa[1] = ad;
    wb[0] = 1.0f - bd; wb[1] = bd;
    wc[0] = 1.0f - cd; wc[1] = cd;
    return true;
}

// ---------------- edge pass: 4 threads per edge, each owns a channel quad ----------------
// lanes 4k..4k+3 share edge e; their 4 float4 gathers per corner form one 64B segment.
__global__ __launch_bounds__(256) void k_edge(const float* __restrict__ pos,
                                              const int* __restrict__ ei,
                                              const float* __restrict__ P,
                                              float* __restrict__ out,
                                              int* __restrict__ cnt) {
    int t = blockIdx.x * 256 + threadIdx.x;
    int e = t >> 2;
    int q = t & 3;                   // channel quad: outputs [q*4, q*4+4)
    if (e >= EE) return;
    int row = ei[e];
    int col = ei[EE + e];
    if (q == 0) atomicAdd(&cnt[row], 1);

    float win;
    int ia[2], jb[2], kc[2];
    float wa[2], wb[2], wc[2];
    if (!edge_geom(pos, row, col, win, ia, jb, kc, wa, wb, wc)) return;

    float4 acc = make_float4(0.f,0.f,0.f,0.f);
    const float* Pq = P + (size_t)col * 16 + q * 4;
    #pragma unroll
    for (int da = 0; da < 2; ++da)
    #pragma unroll
    for (int db = 0; db < 2; ++db)
    #pragma unroll
    for (int dc = 0; dc < 2; ++dc) {
        float w = wa[da] * wb[db] * wc[dc] * win;
        int cell = ia[da]*16 + jb[db]*4 + kc[dc];
        float4 p = *(const float4*)(Pq + (size_t)cell * NN * 16);
        acc.x = fmaf(w, p.x, acc.x);
        acc.y = fmaf(w, p.y, acc.y);
        acc.z = fmaf(w, p.z, acc.z);
        acc.w = fmaf(w, p.w, acc.w);
    }
    float* op = out + (size_t)row * 16 + q * 4;
    atomicAdd(op+0, acc.x);
    atomicAdd(op+1, acc.y);
    atomicAdd(op+2, acc.z);
    atomicAdd(op+3, acc.w);
}

// ---------------- fallback: direct edge kernel, filters from global (slow but correct) ----------------
__global__ __launch_bounds__(256) void k_edge_direct(const float* __restrict__ pos,
                                                     const float* __restrict__ feat,
                                                     const float* __restrict__ filt,
                                                     const int* __restrict__ ei,
                                                     float* __restrict__ out,
                                                     int* __restrict__ cnt) {
    int e = blockIdx.x * 256 + threadIdx.x;
    if (e >= EE) return;
    int row = ei[e];
    int col = ei[EE + e];
    atomicAdd(&cnt[row], 1);

    float win;
    int ia[2], jb[2], kc[2];
    float wa[2], wb[2], wc[2];
    if (!edge_geom(pos, row, col, win, ia, jb, kc, wa, wb, wc)) return;

    float fv[16];
    const float4* fp = (const float4*)(feat + (size_t)col * 16);
    float4 f0 = fp[0], f1 = fp[1], f2 = fp[2], f3 = fp[3];
    fv[0]=f0.x; fv[1]=f0.y; fv[2]=f0.z; fv[3]=f0.w;
    fv[4]=f1.x; fv[5]=f1.y; fv[6]=f1.z; fv[7]=f1.w;
    fv[8]=f2.x; fv[9]=f2.y; fv[10]=f2.z; fv[11]=f2.w;
    fv[12]=f3.x; fv[13]=f3.y; fv[14]=f3.z; fv[15]=f3.w;

    float4 a0 = make_float4(0.f,0.f,0.f,0.f);
    float4 a1 = a0, a2 = a0, a3 = a0;
    for (int da = 0; da < 2; ++da)
    for (int db = 0; db < 2; ++db)
    for (int dc = 0; dc < 2; ++dc) {
        float w = wa[da] * wb[db] * wc[dc] * win;
        const float* fb = filt + (size_t)(ia[da]*16 + jb[db]*4 + kc[dc]) * 256;
        #pragma unroll
        for (int ci = 0; ci < 16; ++ci) {
            float c = w * fv[ci];
            const float4* r4 = (const float4*)(fb + ci * 16);
            float4 w0 = r4[0], w1 = r4[1], w2 = r4[2], w3 = r4[3];
            a0.x = fmaf(c, w0.x, a0.x); a0.y = fmaf(c, w0.y, a0.y);
            a0.z = fmaf(c, w0.z, a0.z); a0.w = fmaf(c, w0.w, a0.w);
            a1.x = fmaf(c, w1.x, a1.x); a1.y = fmaf(c, w1.y, a1.y);
            a1.z = fmaf(c, w1.z, a1.z); a1.w = fmaf(c, w1.w, a1.w);
            a2.x = fmaf(c, w2.x, a2.x); a2.y = fmaf(c, w2.y, a2.y);
            a2.z = fmaf(c, w2.z, a2.z); a2.w = fmaf(c, w2.w, a2.w);
            a3.x = fmaf(c, w3.x, a3.x); a3.y = fmaf(c, w3.y, a3.y);
            a3.z = fmaf(c, w3.z, a3.z); a3.w = fmaf(c, w3.w, a3.w);
        }
    }
    float* op = out + (size_t)row * 16;
    atomicAdd(op+0,  a0.x); atomicAdd(op+1,  a0.y); atomicAdd(op+2,  a0.z); atomicAdd(op+3,  a0.w);
    atomicAdd(op+4,  a1.x); atomicAdd(op+5,  a1.y); atomicAdd(op+6,  a1.z); atomicAdd(op+7,  a1.w);
    atomicAdd(op+8,  a2.x); atomicAdd(op+9,  a2.y); atomicAdd(op+10, a2.z); atomicAdd(op+11, a2.w);
    atomicAdd(op+12, a3.x); atomicAdd(op+13, a3.y); atomicAdd(op+14, a3.z); atomicAdd(op+15, a3.w);
}

// ---------------- divide by max(cnt,1) ----------------
__global__ __launch_bounds__(256) void k_div(float* __restrict__ out, const int* __restrict__ cnt) {
    int i = blockIdx.x * 256 + threadIdx.x;
    if (i >= NN * COUT) return;
    int c = cnt[i >> 4];
    float denom = (c > 1) ? (float)c : 1.0f;
    out[i] = out[i] / denom;
}

extern "C" void kernel_launch(void* const* d_in, const int* in_sizes, int n_in,
                              void* d_out, int out_size, void* d_ws, size_t ws_size,
                              hipStream_t stream) {
    const float* pos  = (const float*)d_in[0];
    const float* feat = (const float*)d_in[1];
    const float* filt = (const float*)d_in[2];
    const int*   ei   = (const int*)d_in[3];
    float* out = (float*)d_out;

    int* cnt = (int*)d_ws;
    size_t need = (size_t)P_OFF + (size_t)64 * NN * 16 * sizeof(float);

    k_zero<<<(NN * COUT + 255) / 256, 256, 0, stream>>>(out, cnt);

    if (ws_size >= need) {
        float* P = (float*)((char*)d_ws + P_OFF);
        dim3 pg((NN + 63) / 64, 4);
        k_pgemm<<<pg, 256, 0, stream>>>(feat, filt, P);
        k_edge<<<(EE * 4 + 255) / 256, 256, 0, stream>>>(pos, ei, P, out, cnt);
    } else {
        k_edge_direct<<<(EE + 255) / 256, 256, 0, stream>>>(pos, feat, filt, ei, out, cnt);
    }

    k_div<<<(NN * COUT + 255) / 256, 256, 0, stream>>>(out, cnt);
}